// Round 2
// baseline (84.662 us; speedup 1.0000x reference)
//
#include <hip/hip_runtime.h>

// N-body all-pairs gravitational force, N=8192, fp32.
//
// Round-9: raise independent-chain count per SIMD. r7 vs r8 was confounded:
// waves/SIMD x IBLK (chains/SIMD) stayed 8 in both, and both fit
// time = k_iters/SIMD * max(issue, lambda/waves) with lambda ~= 700 cyc
// (latency-bound). This round: 16 chains/SIMD.
//  - BLOCK=256, IBLK=4 -> 1024 i's/block, 8 i-tiles
//  - JSPLIT=128 -> JPER=64 j's/block, 1KB LDS tile, one barrier
//  - grid 8x128 = 1024 blocks x 4 waves = 4 waves/SIMD x 4 chains = 16
//  - partials [128][OUTE] = 12.6 MB (+6.3 MB vs r8; ~+1us reduce)
//  - per-pair math bit-identical (absmax should stay 0.125)
// Prediction: nbody ~36.5 -> ~19-22us, dur_us 80 -> ~62-66.
// If unchanged: chains model wrong -> disasm + packed v_pk_fma_f32 next.

constexpr int   NBODY   = 8192;
constexpr int   BLOCK   = 256;
constexpr int   IBLK    = 4;
constexpr int   IBODIES = BLOCK * IBLK;        // 1024 i's per block
constexpr int   JSPLIT  = 128;
constexpr int   JPER    = NBODY / JSPLIT;      // 64 j's per block
constexpr float SOFT2   = 0.01f * 0.01f;
constexpr int   OUTE    = NBODY * 3;           // 24576

__global__ __launch_bounds__(BLOCK, 4) void nbody_forces(
    const float* __restrict__ pos,       // [N,3]
    const float* __restrict__ mass,      // [N]
    float*       __restrict__ part)      // [JSPLIT][N*3] partials
{
    const int tid   = threadIdx.x;
    const int iBase = blockIdx.x * IBODIES + tid;
    const int j0    = blockIdx.y * JPER;

    __shared__ float4 sh[JPER];
    if (tid < JPER) {                    // 64 of 256 threads stage
        const int j = j0 + tid;
        sh[tid] = make_float4(pos[3 * j + 0], pos[3 * j + 1], pos[3 * j + 2], mass[j]);
    }

    float px[IBLK], py[IBLK], pz[IBLK];
    #pragma unroll
    for (int b = 0; b < IBLK; ++b) {
        const int i = iBase + b * BLOCK;
        px[b] = pos[3 * i + 0];
        py[b] = pos[3 * i + 1];
        pz[b] = pos[3 * i + 2];
    }
    __syncthreads();

    float fx[IBLK], fy[IBLK], fz[IBLK];
    #pragma unroll
    for (int b = 0; b < IBLK; ++b) { fx[b] = 0.f; fy[b] = 0.f; fz[b] = 0.f; }

    #pragma unroll 4
    for (int k = 0; k < JPER; ++k) {
        const float4 p = sh[k];            // uniform addr -> HW broadcast
        #pragma unroll
        for (int b = 0; b < IBLK; ++b) {   // 4 chains x 4 waves/SIMD = 16
            const float dx = p.x - px[b];
            const float dy = p.y - py[b];
            const float dz = p.z - pz[b];
            const float d2 = fmaf(dx, dx, fmaf(dy, dy, fmaf(dz, dz, SOFT2)));
            const float inv = __builtin_amdgcn_rsqf(d2);    // v_rsq_f32
            const float s   = p.w * inv * inv * inv;        // G = 1
            fx[b] = fmaf(s, dx, fx[b]);
            fy[b] = fmaf(s, dy, fy[b]);
            fz[b] = fmaf(s, dz, fz[b]);
            // j == i: diff = 0 -> contribution 0, matches reference.
        }
    }

    float* dst = part + (size_t)blockIdx.y * OUTE;
    #pragma unroll
    for (int b = 0; b < IBLK; ++b) {
        const int i = iBase + b * BLOCK;
        dst[3 * i + 0] = fx[b];
        dst[3 * i + 1] = fy[b];
        dst[3 * i + 2] = fz[b];
    }
}

__global__ __launch_bounds__(256) void reduce_kernel(
    const float* __restrict__ part,      // [JSPLIT][OUTE]
    float*       __restrict__ out)       // [OUTE]
{
    const int e = blockIdx.x * blockDim.x + threadIdx.x;   // 0..OUTE-1
    float s = 0.f;
    #pragma unroll 8
    for (int k = 0; k < JSPLIT; ++k)
        s += part[(size_t)k * OUTE + e];
    out[e] = s;
}

extern "C" void kernel_launch(void* const* d_in, const int* in_sizes, int n_in,
                              void* d_out, int out_size, void* d_ws, size_t ws_size,
                              hipStream_t stream) {
    const float* pos  = (const float*)d_in[0];
    const float* mass = (const float*)d_in[1];
    float* out = (float*)d_out;

    float* part = (float*)d_ws;          // [JSPLIT][OUTE] = 12.6 MB

    dim3 grid(NBODY / IBODIES, JSPLIT);  // (8, 128) = 1024 blocks
    nbody_forces<<<grid, BLOCK, 0, stream>>>(pos, mass, part);

    reduce_kernel<<<OUTE / 256, 256, 0, stream>>>(part, out);
}